// Round 10
// baseline (47.280 us; speedup 1.0000x reference)
//
#include <hip/hip_runtime.h>

#define KCLS 21
#define HW (512 * 512)
#define BATCH 8
#define NBLK 2048
#define BLKSZ 256
#define BPI (NBLK / BATCH)             // 256 blocks per image
#define PIXB (HW / BPI)                // 1024 px per block
#define PXT 2                          // 2 px per thread per iteration (float2)
#define ITERS (PIXB / (BLKSZ * PXT))   // 2

// ws layout: u32 inter[8*21] | u32 aout[8*21] | u32 atgt[8*21] | f32 S[8*21]

__global__ __launch_bounds__(BLKSZ, 8) void dicece_histo(
    const float* __restrict__ pr, const int* __restrict__ gt,
    unsigned int* __restrict__ ws_inter, unsigned int* __restrict__ ws_aout,
    unsigned int* __restrict__ ws_atgt, float* __restrict__ ws_S)
{
    __shared__ unsigned int s_ti[KCLS];    // inter<<12 | tgt (block counts <= 1024)
    __shared__ unsigned int s_aout[KCLS];
    __shared__ float s_S[KCLS];
    const int t = threadIdx.x;
    if (t < KCLS) { s_ti[t] = 0u; s_aout[t] = 0u; s_S[t] = 0.f; }
    __syncthreads();

    const int b = blockIdx.x / BPI;
    const int chunk = blockIdx.x - b * BPI;
    const float* __restrict__ pb = pr + (size_t)b * KCLS * HW + chunk * PIXB;
    const int*   __restrict__ gb = gt + (size_t)b * HW + chunk * PIXB;

    #pragma unroll 1
    for (int it = 0; it < ITERS; ++it) {
        const int p = (it * BLKSZ + t) * PXT;

        // 21 float2 streams: 512 B per wave-instr, half the issue slots of R8
        float x[KCLS][PXT];
        #pragma unroll
        for (int k = 0; k < KCLS; ++k)
            *reinterpret_cast<float2*>(&x[k][0]) =
                *reinterpret_cast<const float2*>(pb + (size_t)k * HW + p);
        int g[PXT];
        *reinterpret_cast<int2*>(&g[0]) = *reinterpret_cast<const int2*>(gb + p);

        #pragma unroll
        for (int j = 0; j < PXT; ++j) {
            // max via 3-ary tree (fuses to v_max3_f32): ~10 ops
            const float a0 = fmaxf(fmaxf(x[0][j],  x[1][j]),  x[2][j]);
            const float a1 = fmaxf(fmaxf(x[3][j],  x[4][j]),  x[5][j]);
            const float a2 = fmaxf(fmaxf(x[6][j],  x[7][j]),  x[8][j]);
            const float a3 = fmaxf(fmaxf(x[9][j],  x[10][j]), x[11][j]);
            const float a4 = fmaxf(fmaxf(x[12][j], x[13][j]), x[14][j]);
            const float a5 = fmaxf(fmaxf(x[15][j], x[16][j]), x[17][j]);
            const float a6 = fmaxf(fmaxf(x[18][j], x[19][j]), x[20][j]);
            const float b0 = fmaxf(fmaxf(a0, a1), a2);
            const float b1 = fmaxf(fmaxf(a3, a4), a5);
            const float m  = fmaxf(fmaxf(b0, b1), a6);

            // first-occurrence argmax: descending eq-scan
            int am = 20;
            #pragma unroll
            for (int k = 19; k >= 0; --k) am = (x[k][j] == m) ? k : am;

            float s = 0.f;
            #pragma unroll
            for (int k = 0; k < KCLS; ++k) s += __expf(x[k][j] - m);

            const int gj = g[j];
            float xg = x[0][j];
            #pragma unroll
            for (int k = 1; k < KCLS; ++k) xg = (k == gj) ? x[k][j] : xg;
            const float logp = xg - m - __logf(s);

            // 3 LDS atomics/px, branch-free
            atomicAdd(&s_ti[gj], (am == gj) ? ((1u << 12) | 1u) : 1u);
            atomicAdd(&s_aout[am], 1u);
            atomicAdd(&s_S[gj], logp);
        }
    }
    __syncthreads();

    if (t < KCLS) {
        const unsigned int ti = s_ti[t];
        atomicAdd(&ws_inter[b * KCLS + t], ti >> 12);
        atomicAdd(&ws_atgt [b * KCLS + t], ti & 0xFFFu);
        atomicAdd(&ws_aout [b * KCLS + t], s_aout[t]);
        atomicAdd(&ws_S    [b * KCLS + t], s_S[t]);
    }
}

__global__ void dicece_final(
    const unsigned int* __restrict__ ws_inter, const unsigned int* __restrict__ ws_aout,
    const unsigned int* __restrict__ ws_atgt, const float* __restrict__ ws_S,
    float* __restrict__ out)
{
    const int k = threadIdx.x;   // one wave; lanes >= 21 contribute 0
    float w = 0.f, Nk = 0.f, Sk = 0.f;
    if (k < KCLS) {
        float dsum = 0.f;
        unsigned int nk = 0u;
        #pragma unroll
        for (int b = 0; b < BATCH; ++b) {
            const float inter = (float)ws_inter[b * KCLS + k];
            const float ao    = (float)ws_aout [b * KCLS + k];
            const float at    = (float)ws_atgt [b * KCLS + k];
            nk += ws_atgt[b * KCLS + k];
            dsum += 2.f * inter / (ao + at + 1e-10f);   // union+inter == ao+at
            Sk += ws_S[b * KCLS + k];
        }
        w  = 1.f - dsum * 0.125f;   // weight = 1 - dice_class (SAMPLES=8)
        Nk = (float)nk;
    }
    float num = w * Sk, den = w * Nk, wsum = w;
    #pragma unroll
    for (int off = 32; off > 0; off >>= 1) {
        num  += __shfl_down(num, off);
        den  += __shfl_down(den, off);
        wsum += __shfl_down(wsum, off);
    }
    // BETA * mean(weight) + (-(sum w*logp) / (sum w*N))
    if (k == 0) out[0] = wsum / (float)KCLS - num / den;
}

extern "C" void kernel_launch(void* const* d_in, const int* in_sizes, int n_in,
                              void* d_out, int out_size, void* d_ws, size_t ws_size,
                              hipStream_t stream) {
    const float* pr = (const float*)d_in[0];
    const int*   gt = (const int*)d_in[1];
    float* out = (float*)d_out;

    unsigned int* ws_inter = (unsigned int*)d_ws;
    unsigned int* ws_aout  = ws_inter + BATCH * KCLS;
    unsigned int* ws_atgt  = ws_aout  + BATCH * KCLS;
    float*        ws_S     = (float*)(ws_atgt + BATCH * KCLS);

    hipMemsetAsync(d_ws, 0, (size_t)(4 * BATCH * KCLS) * sizeof(float), stream);
    dicece_histo<<<NBLK, BLKSZ, 0, stream>>>(pr, gt, ws_inter, ws_aout, ws_atgt, ws_S);
    dicece_final<<<1, 64, 0, stream>>>(ws_inter, ws_aout, ws_atgt, ws_S, out);
}